// Round 5
// baseline (233.385 us; speedup 1.0000x reference)
//
#include <hip/hip_runtime.h>

#define IMG_W 1024
#define IMG_H 1024
#define BATCH 32
#define ROWS 8   // output rows per thread

typedef float vfloat4 __attribute__((ext_vector_type(4)));

__global__ __launch_bounds__(256) void conv3x3_kernel(
    const float* __restrict__ X,
    const float* __restrict__ wt,
    float* __restrict__ out)
{
    const int y0 = blockIdx.x * ROWS;      // first output row of this block
    const int b  = blockIdx.y;             // batch
    const int c0 = threadIdx.x * 4;        // first of 4 output cols

    const float* img = X + (size_t)b * IMG_H * IMG_W;

    const float w0 = wt[0], w1 = wt[1], w2 = wt[2];
    const float w3 = wt[3], w4 = wt[4], w5 = wt[5];
    const float w6 = wt[6], w7 = wt[7], w8 = wt[8];

    // R[i] holds input row y0-1+i, cols c0-1 .. c0+4
    float R[ROWS + 2][6];

#pragma unroll
    for (int i = 0; i < ROWS + 2; ++i) {
        const int ry = y0 + i - 1;
        if (ry >= 0 && ry < IMG_H) {
            const float* p = img + (size_t)ry * IMG_W + c0;
            const vfloat4 v = *(const vfloat4*)p;
            R[i][1] = v.x; R[i][2] = v.y; R[i][3] = v.z; R[i][4] = v.w;
            R[i][0] = (c0 > 0)         ? p[-1] : 0.f;
            R[i][5] = (c0 + 4 < IMG_W) ? p[4]  : 0.f;
        } else {
            R[i][0] = R[i][1] = R[i][2] = R[i][3] = R[i][4] = R[i][5] = 0.f;
        }
    }

    __builtin_amdgcn_sched_barrier(0);

    float* obase = out + ((size_t)b * IMG_H + y0) * IMG_W + c0;

#pragma unroll
    for (int i = 0; i < ROWS; ++i) {
        vfloat4 r;
#pragma unroll
        for (int j = 0; j < 4; ++j) {
            r[j] = w0 * R[i][j]     + w1 * R[i][j + 1]     + w2 * R[i][j + 2]
                 + w3 * R[i + 1][j] + w4 * R[i + 1][j + 1] + w5 * R[i + 1][j + 2]
                 + w6 * R[i + 2][j] + w7 * R[i + 2][j + 1] + w8 * R[i + 2][j + 2];
        }
        // A/B vs round 4: PLAIN store instead of __builtin_nontemporal_store.
        // The harness fill sustains 6.7 TB/s with plain streaming stores; NT
        // was the one untested factor common to every ~80 µs variant.
        *(vfloat4*)(obase + (size_t)i * IMG_W) = r;
    }
}

extern "C" void kernel_launch(void* const* d_in, const int* in_sizes, int n_in,
                              void* d_out, int out_size, void* d_ws, size_t ws_size,
                              hipStream_t stream) {
    const float* X  = (const float*)d_in[0];
    const float* wt = (const float*)d_in[1];
    float* out = (float*)d_out;

    dim3 grid(IMG_H / ROWS, BATCH);   // 128 x 32 = 4096 blocks
    dim3 block(256);                  // 256 threads * 4 cols = 1024 cols
    conv3x3_kernel<<<grid, block, 0, stream>>>(X, wt, out);
}

// Round 6
// 230.501 us; speedup vs baseline: 1.0125x; 1.0125x over previous
//
#include <hip/hip_runtime.h>

#define IMG_W 1024
#define IMG_H 1024
#define BATCH 32
#define ROWS 8   // output rows per thread

typedef float vfloat4 __attribute__((ext_vector_type(4)));

__global__ __launch_bounds__(256) void conv3x3_kernel(
    const float* __restrict__ X,
    const float* __restrict__ wt,
    float* __restrict__ out)
{
    const int y0   = blockIdx.x * ROWS;     // first output row of this block
    const int b    = blockIdx.y;            // batch
    const int c0   = threadIdx.x * 4;       // first of 4 output cols
    const int lane = threadIdx.x & 63;

    const float* img = X + (size_t)b * IMG_H * IMG_W;

    const float w0 = wt[0], w1 = wt[1], w2 = wt[2];
    const float w3 = wt[3], w4 = wt[4], w5 = wt[5];
    const float w6 = wt[6], w7 = wt[7], w8 = wt[8];

    // ---- phase 1: issue ALL vector loads back-to-back (max bytes in flight).
    // Halo comes from neighbor lanes via shuffle later; only the wave-boundary
    // lanes (0/63) issue a 2-lane-divergent scalar load (2 cache lines, vs the
    // 64-line gather the old per-thread halo loads generated).
    vfloat4 V[ROWS + 2];
    float   HL[ROWS + 2];   // left-halo value, meaningful on lane 0 only
    float   HR[ROWS + 2];   // right-halo value, meaningful on lane 63 only

#pragma unroll
    for (int i = 0; i < ROWS + 2; ++i) {
        const int ry = y0 + i - 1;
        float hl = 0.f, hr = 0.f;
        if (ry >= 0 && ry < IMG_H) {
            const float* p = img + (size_t)ry * IMG_W + c0;
            V[i] = *(const vfloat4*)p;
            if (lane == 0  && c0 > 0)         hl = p[-1];
            if (lane == 63 && c0 + 4 < IMG_W) hr = p[4];
        } else {
            V[i] = (vfloat4){0.f, 0.f, 0.f, 0.f};
        }
        HL[i] = hl; HR[i] = hr;
    }

    // Opaque uses: pin every load result HERE so the compiler cannot sink the
    // loads into the compute loop (R3/R4 post-mortem: VGPR 36/52 proved the
    // loads were being re-sunk at IR level; sched_barrier(0) instead pinned
    // the whole schedule and cost ~10 us). This only forces liveness/order at
    // this point — the scheduler stays free elsewhere.
    asm volatile("" : "+v"(V[0]), "+v"(V[1]), "+v"(V[2]), "+v"(V[3]), "+v"(V[4]),
                      "+v"(V[5]), "+v"(V[6]), "+v"(V[7]), "+v"(V[8]), "+v"(V[9]));
    asm volatile("" : "+v"(HL[0]), "+v"(HL[1]), "+v"(HL[2]), "+v"(HL[3]), "+v"(HL[4]),
                      "+v"(HL[5]), "+v"(HL[6]), "+v"(HL[7]), "+v"(HL[8]), "+v"(HL[9]));
    asm volatile("" : "+v"(HR[0]), "+v"(HR[1]), "+v"(HR[2]), "+v"(HR[3]), "+v"(HR[4]),
                      "+v"(HR[5]), "+v"(HR[6]), "+v"(HR[7]), "+v"(HR[8]), "+v"(HR[9]));

    // ---- phase 2: expand each row once into the 6-wide window via shuffle ----
    float R[ROWS + 2][6];
#pragma unroll
    for (int i = 0; i < ROWS + 2; ++i) {
        float left  = __shfl_up(V[i].w, 1);    // lane-1's col c0-1
        float right = __shfl_down(V[i].x, 1);  // lane+1's col c0+4
        left  = (lane == 0)  ? HL[i] : left;   // wave boundary / image edge
        right = (lane == 63) ? HR[i] : right;
        R[i][0] = left;  R[i][1] = V[i].x; R[i][2] = V[i].y;
        R[i][3] = V[i].z; R[i][4] = V[i].w; R[i][5] = right;
    }

    // ---- phase 3: pure-FMA compute + NT store stream (R0's fast tail) ----
    float* obase = out + ((size_t)b * IMG_H + y0) * IMG_W + c0;

#pragma unroll
    for (int i = 0; i < ROWS; ++i) {
        vfloat4 r;
#pragma unroll
        for (int j = 0; j < 4; ++j) {
            r[j] = w0 * R[i][j]     + w1 * R[i][j + 1]     + w2 * R[i][j + 2]
                 + w3 * R[i + 1][j] + w4 * R[i + 1][j + 1] + w5 * R[i + 1][j + 2]
                 + w6 * R[i + 2][j] + w7 * R[i + 2][j + 1] + w8 * R[i + 2][j + 2];
        }
        __builtin_nontemporal_store(r, (vfloat4*)(obase + (size_t)i * IMG_W));
    }
}

extern "C" void kernel_launch(void* const* d_in, const int* in_sizes, int n_in,
                              void* d_out, int out_size, void* d_ws, size_t ws_size,
                              hipStream_t stream) {
    const float* X  = (const float*)d_in[0];
    const float* wt = (const float*)d_in[1];
    float* out = (float*)d_out;

    dim3 grid(IMG_H / ROWS, BATCH);   // 128 x 32 = 4096 blocks
    dim3 block(256);                  // 256 threads * 4 cols = 1024 cols
    conv3x3_kernel<<<grid, block, 0, stream>>>(X, wt, out);
}